// Round 7
// baseline (202.570 us; speedup 1.0000x reference)
//
#include <hip/hip_runtime.h>
#include <math.h>

// PhaseShift: out = unwrap(atan2(xi,xr) - atan2(xi[ch0],xr[ch0]), axis=F)
// Shapes: [N=16, CH=4, F=513, T=512] fp32.
//
// Occupancy round: R6 was latency-bound at 16 waves/CU (grid 256 x 16
// waves = 50% cap; profiled 34%). Re-tile to 512 blocks x 1024 threads =
// 8192 waves = 32 waves/CU (100% cap): block = (n, t-tile of 16),
// 1024 threads = 16 t-lanes x 64 F-segments of 8 rows (seg 63 takes 9).
// Streaming skeleton unchanged (NO per-thread arrays -- R1/R2/R4 spilled):
// pass 1 streams pc+acc to out (ch0 = exact 0), LDS scan of per-segment
// correction sums, pass 2 RMWs out += run (L2-resident).
// dd bit-sequence bit-identical (channel-fused a0, bounded exact mod,
// boundary pprev = same expression) -- no pi-boundary lottery re-roll.

#define NN    16
#define CHN   4
#define FF    513
#define TT    512
#define PLANE (FF * TT)      // 262656
#define NSEG  64
#define SEGB  8              // segs 0..62: 8 rows; seg 63: 9 rows
#define TL    16             // t-lanes per block

__device__ __forceinline__ float phase_corr(float dd) {
    // np.unwrap step: ddmod = pymod(dd+pi, 2pi) - pi; edge rule; gate |dd|<pi.
    // dd in (-4pi, 4pi) -> x = dd+pi in (-3pi, 5pi): <=2 exact +-2pi steps.
    const float PIF  = 3.14159265358979323846f;   // 0x40490FDB
    const float TPIF = 6.28318530717958647692f;   // 0x40C90FDB = 2*PIF exactly
    float x = dd + PIF;
    x = (x >= TPIF) ? x - TPIF : x;
    x = (x >= TPIF) ? x - TPIF : x;
    x = (x < 0.0f)  ? x + TPIF : x;
    x = (x < 0.0f)  ? x + TPIF : x;
    float ddmod = x - PIF;
    if (ddmod == -PIF && dd > 0.0f) ddmod = PIF;
    return (fabsf(dd) < PIF) ? 0.0f : (ddmod - dd);
}

__global__ __launch_bounds__(1024) void phase_unwrap_kernel(
    const float* __restrict__ xr, const float* __restrict__ xi,
    float* __restrict__ out)
{
    const int tid   = threadIdx.x;
    const int tl    = tid & (TL - 1);   // t within tile
    const int seg   = tid >> 4;         // 0..63 F-segment
    const int bid   = blockIdx.x;
    const int ttile = bid & 31;         // 32 tiles of 16 t
    const int n     = bid >> 5;
    const int t     = ttile * TL + tl;

    const unsigned base = (unsigned)(n * CHN * PLANE) + (unsigned)t;
    const int f0  = seg * SEGB;
    const int cnt = (seg == NSEG - 1) ? (FF - f0) : SEGB;   // 8, last 9

    __shared__ float segsum[3][NSEG][TL];

    // Boundary phases at f0-1 (segs 1..63).
    float pprev0 = 0.0f, pprev1 = 0.0f, pprev2 = 0.0f;
    if (seg > 0) {
        const unsigned off = base + (unsigned)(f0 - 1) * TT;
        const float a0 = atan2f(xi[off], xr[off]);
        pprev0 = atan2f(xi[off + 1u * PLANE], xr[off + 1u * PLANE]) - a0;
        pprev1 = atan2f(xi[off + 2u * PLANE], xr[off + 2u * PLANE]) - a0;
        pprev2 = atan2f(xi[off + 3u * PLANE], xr[off + 3u * PLANE]) - a0;
    }

    // Pass 1: shared a0, three correction chains, stream stores.
    float acc0 = 0.0f, acc1 = 0.0f, acc2 = 0.0f;
    unsigned off = base + (unsigned)f0 * TT;
    #pragma unroll 8
    for (int k = 0; k < cnt; ++k, off += TT) {
        const float a0  = atan2f(xi[off], xr[off]);
        const float pc0 = atan2f(xi[off + 1u * PLANE], xr[off + 1u * PLANE]) - a0;
        const float pc1 = atan2f(xi[off + 2u * PLANE], xr[off + 2u * PLANE]) - a0;
        const float pc2 = atan2f(xi[off + 3u * PLANE], xr[off + 3u * PLANE]) - a0;
        if (seg > 0 || k > 0) {            // k>0 folds in unrolled bodies
            acc0 += phase_corr(pc0 - pprev0);
            acc1 += phase_corr(pc1 - pprev1);
            acc2 += phase_corr(pc2 - pprev2);
        }
        __builtin_nontemporal_store(0.0f, &out[off]);   // ch0: final, never re-read
        out[off + 1u * PLANE] = pc0 + acc0;             // cached: RMW re-reads
        out[off + 2u * PLANE] = pc1 + acc1;
        out[off + 3u * PLANE] = pc2 + acc2;
        pprev0 = pc0; pprev1 = pc1; pprev2 = pc2;
    }

    segsum[0][seg][tl] = acc0;
    segsum[1][seg][tl] = acc1;
    segsum[2][seg][tl] = acc2;
    __syncthreads();

    if (seg > 0) {
        // Exclusive prefix over segments, ascending v (broadcast LDS reads).
        float run0 = 0.0f, run1 = 0.0f, run2 = 0.0f;
        for (int v = 0; v < NSEG - 1; ++v) {
            if (v < seg) {
                run0 += segsum[0][v][tl];
                run1 += segsum[1][v][tl];
                run2 += segsum[2][v][tl];
            }
        }
        // Pass 2: RMW our own freshly-written rows (L2-hot), nt final store.
        unsigned o2 = base + (unsigned)f0 * TT;
        #pragma unroll 8
        for (int k = 0; k < cnt; ++k, o2 += TT) {
            const float v0 = out[o2 + 1u * PLANE] + run0;
            const float v1 = out[o2 + 2u * PLANE] + run1;
            const float v2 = out[o2 + 3u * PLANE] + run2;
            __builtin_nontemporal_store(v0, &out[o2 + 1u * PLANE]);
            __builtin_nontemporal_store(v1, &out[o2 + 2u * PLANE]);
            __builtin_nontemporal_store(v2, &out[o2 + 3u * PLANE]);
        }
    }
}

extern "C" void kernel_launch(void* const* d_in, const int* in_sizes, int n_in,
                              void* d_out, int out_size, void* d_ws, size_t ws_size,
                              hipStream_t stream) {
    const float* xr = (const float*)d_in[0];
    const float* xi = (const float*)d_in[1];
    float* out = (float*)d_out;

    dim3 grid(NN * (TT / TL));   // 512 blocks = 2 blocks/CU
    dim3 block(1024);            // 64 segments x 16 t-lanes
    phase_unwrap_kernel<<<grid, block, 0, stream>>>(xr, xi, out);
}

// Round 8
// 93.086 us; speedup vs baseline: 2.1762x; 2.1762x over previous
//
#include <hip/hip_runtime.h>
#include <math.h>

// PhaseShift: out = unwrap(atan2(xi,xr) - atan2(xi[ch0],xr[ch0]), axis=F)
// Shapes: [N=16, CH=4, F=513, T=512] fp32.
//
// R6 skeleton + ILP round. R7 lesson: <32 contiguous t per access = 2x
// over-fetch on 128B lines (FETCH/WRITE doubled) -- never again. So to add
// parallelism per wave WITHOUT narrowing the access footprint, each lane
// now owns 2 adjacent t via float2: 16 lane-groups x 2 cols = 32 t, every
// load/store instruction = 16 lanes x 8B = one full 128B line. 64 segments
// of 8 rows (seg 63 takes the 513th row as a peeled extra). Per lane-row:
// 8 independent atan2 chains (vs 4) and half the memory instructions.
// NO per-thread arrays (R1/R2/R4 spilled). Streaming pass 1 (ch0 = exact
// zeros, nt), LDS scan of per-segment correction sums, pass 2 RMW (+run,
// nt final store). dd bit-sequence unchanged (channel-fused a0, bounded
// exact mod, boundary pprev same expression) -- no pi-boundary re-roll.

#define NN    16
#define CHN   4
#define FF    513
#define TT    512
#define PLANE (FF * TT)      // 262656
#define P2    (PLANE / 2)    // 131328 float2
#define R2    (TT / 2)       // 256 float2 per row
#define NSEG  64
#define SEGB  8              // segs 0..62: 8 rows; seg 63: 9 rows

__device__ __forceinline__ float phase_corr(float dd) {
    // np.unwrap step: ddmod = pymod(dd+pi, 2pi) - pi; edge rule; gate |dd|<pi.
    // dd in (-4pi, 4pi) -> x = dd+pi in (-3pi, 5pi): <=2 exact +-2pi steps.
    const float PIF  = 3.14159265358979323846f;   // 0x40490FDB
    const float TPIF = 6.28318530717958647692f;   // 0x40C90FDB = 2*PIF exactly
    float x = dd + PIF;
    x = (x >= TPIF) ? x - TPIF : x;
    x = (x >= TPIF) ? x - TPIF : x;
    x = (x < 0.0f)  ? x + TPIF : x;
    x = (x < 0.0f)  ? x + TPIF : x;
    float ddmod = x - PIF;
    if (ddmod == -PIF && dd > 0.0f) ddmod = PIF;
    return (fabsf(dd) < PIF) ? 0.0f : (ddmod - dd);
}

__global__ __launch_bounds__(1024) void phase_unwrap_kernel(
    const float* __restrict__ xr, const float* __restrict__ xi,
    float* __restrict__ out)
{
    const int tid   = threadIdx.x;
    const int l     = tid & 15;      // lane-group: 2 adjacent t
    const int seg   = tid >> 4;      // 0..63 F-segment
    const int bid   = blockIdx.x;
    const int ttile = bid & 15;      // 16 tiles of 32 t
    const int n     = bid >> 4;

    const float2* __restrict__ xr2  = (const float2*)xr;
    const float2* __restrict__ xi2  = (const float2*)xi;
    float2* __restrict__       out2 = (float2*)out;

    const unsigned base2 = (unsigned)(n * CHN * P2) + (unsigned)(ttile * 16 + l);
    const int f0 = seg * SEGB;

    __shared__ float2 segsum[3][NSEG][16];   // 24 KB

    // pprev per channel per column
    float p0x = 0.f, p0y = 0.f, p1x = 0.f, p1y = 0.f, p2x = 0.f, p2y = 0.f;
    if (seg > 0) {
        const unsigned o = base2 + (unsigned)(f0 - 1) * R2;
        const float2 r0 = xr2[o],           i0 = xi2[o];
        const float2 r1 = xr2[o + P2],      i1 = xi2[o + P2];
        const float2 r2 = xr2[o + 2u * P2], i2 = xi2[o + 2u * P2];
        const float2 r3 = xr2[o + 3u * P2], i3 = xi2[o + 3u * P2];
        const float a0x = atan2f(i0.x, r0.x), a0y = atan2f(i0.y, r0.y);
        p0x = atan2f(i1.x, r1.x) - a0x;  p0y = atan2f(i1.y, r1.y) - a0y;
        p1x = atan2f(i2.x, r2.x) - a0x;  p1y = atan2f(i2.y, r2.y) - a0y;
        p2x = atan2f(i3.x, r3.x) - a0x;  p2y = atan2f(i3.y, r3.y) - a0y;
    }

    float acc0x = 0.f, acc0y = 0.f, acc1x = 0.f, acc1y = 0.f, acc2x = 0.f, acc2y = 0.f;

    auto row = [&](unsigned o, bool first) {
        const float2 r0 = xr2[o],           i0 = xi2[o];
        const float2 r1 = xr2[o + P2],      i1 = xi2[o + P2];
        const float2 r2 = xr2[o + 2u * P2], i2 = xi2[o + 2u * P2];
        const float2 r3 = xr2[o + 3u * P2], i3 = xi2[o + 3u * P2];
        const float a0x = atan2f(i0.x, r0.x), a0y = atan2f(i0.y, r0.y);
        const float c0x = atan2f(i1.x, r1.x) - a0x, c0y = atan2f(i1.y, r1.y) - a0y;
        const float c1x = atan2f(i2.x, r2.x) - a0x, c1y = atan2f(i2.y, r2.y) - a0y;
        const float c2x = atan2f(i3.x, r3.x) - a0x, c2y = atan2f(i3.y, r3.y) - a0y;
        if (!first) {
            acc0x += phase_corr(c0x - p0x);  acc0y += phase_corr(c0y - p0y);
            acc1x += phase_corr(c1x - p1x);  acc1y += phase_corr(c1y - p1y);
            acc2x += phase_corr(c2x - p2x);  acc2y += phase_corr(c2y - p2y);
        }
        __builtin_nontemporal_store(0.0, (double*)(out2 + o));  // ch0: exact zeros
        out2[o + P2]      = make_float2(c0x + acc0x, c0y + acc0y);  // cached: RMW re-reads
        out2[o + 2u * P2] = make_float2(c1x + acc1x, c1y + acc1y);
        out2[o + 3u * P2] = make_float2(c2x + acc2x, c2y + acc2y);
        p0x = c0x; p0y = c0y; p1x = c1x; p1y = c1y; p2x = c2x; p2y = c2y;
    };

    unsigned o = base2 + (unsigned)f0 * R2;
    #pragma unroll
    for (int k = 0; k < SEGB; ++k, o += R2)
        row(o, seg == 0 && k == 0);
    if (seg == NSEG - 1)          // peeled 9th row (f = 512)
        row(o, false);

    segsum[0][seg][l] = make_float2(acc0x, acc0y);
    segsum[1][seg][l] = make_float2(acc1x, acc1y);
    segsum[2][seg][l] = make_float2(acc2x, acc2y);
    __syncthreads();

    if (seg > 0) {
        float r0x = 0.f, r0y = 0.f, r1x = 0.f, r1y = 0.f, r2x = 0.f, r2y = 0.f;
        for (int v = 0; v < NSEG - 1; ++v) {
            if (v < seg) {
                const float2 s0 = segsum[0][v][l];
                const float2 s1 = segsum[1][v][l];
                const float2 s2 = segsum[2][v][l];
                r0x += s0.x; r0y += s0.y;
                r1x += s1.x; r1y += s1.y;
                r2x += s2.x; r2y += s2.y;
            }
        }
        auto rmw = [&](unsigned oo) {
            float2 v0 = out2[oo + P2], v1 = out2[oo + 2u * P2], v2 = out2[oo + 3u * P2];
            v0.x += r0x; v0.y += r0y;
            v1.x += r1x; v1.y += r1y;
            v2.x += r2x; v2.y += r2y;
            __builtin_nontemporal_store(__builtin_bit_cast(double, v0), (double*)(out2 + oo + P2));
            __builtin_nontemporal_store(__builtin_bit_cast(double, v1), (double*)(out2 + oo + 2u * P2));
            __builtin_nontemporal_store(__builtin_bit_cast(double, v2), (double*)(out2 + oo + 3u * P2));
        };
        unsigned o2 = base2 + (unsigned)f0 * R2;
        #pragma unroll
        for (int k = 0; k < SEGB; ++k, o2 += R2)
            rmw(o2);
        if (seg == NSEG - 1)
            rmw(o2);
    }
}

extern "C" void kernel_launch(void* const* d_in, const int* in_sizes, int n_in,
                              void* d_out, int out_size, void* d_ws, size_t ws_size,
                              hipStream_t stream) {
    const float* xr = (const float*)d_in[0];
    const float* xi = (const float*)d_in[1];
    float* out = (float*)d_out;

    dim3 grid(NN * (TT / 32));   // 256 blocks
    dim3 block(1024);            // 64 segments x 16 lane-groups (2 t each)
    phase_unwrap_kernel<<<grid, block, 0, stream>>>(xr, xi, out);
}